// Round 1
// baseline (281.888 us; speedup 1.0000x reference)
//
#include <hip/hip_runtime.h>
#include <cstdint>

// Jagged per-segment argmax.
// values: [total] f32, prefix_sum: [n_seg] cumulative END offsets (sorted,
// last == total). Output: [n_seg] int32 flat index of FIRST max element in
// each segment; empty segments (duplicate offsets) -> INT32_MAX (the
// jax.ops.segment_min identity for int32 — verified from the reference's
// absmax signature, NOT `total` as the docstring claims).
//
// Design: one 64-lane wave per segment (mean segment length == 64).
// Lane-strided coalesced loads; per-lane (max, first-idx); 6-step
// __shfl_xor butterfly reduce with (val desc, idx asc) ordering.

#define WAVE 64

__global__ __launch_bounds__(256) void jagged_argmax_kernel(
    const float* __restrict__ values,
    const int*   __restrict__ ps32,   // prefix_sum viewed as int32 words
    int n_seg,
    int* __restrict__ out)
{
    const int wave = (int)((blockIdx.x * blockDim.x + threadIdx.x) >> 6);
    const int lane = (int)(threadIdx.x & 63);
    if (wave >= n_seg) return;

    // Layout detect: int64 little-endian => word 1 is the high word of
    // prefix_sum[0] (value < 2^31) == 0. int32 => word 1 = prefix_sum[1] >= 1.
    const bool is64 = (ps32[1] == 0);
    const long long* ps64 = (const long long*)ps32;

    int start, end;
    if (is64) {
        start = (wave > 0) ? (int)ps64[wave - 1] : 0;
        end   = (int)ps64[wave];
    } else {
        start = (wave > 0) ? ps32[wave - 1] : 0;
        end   = ps32[wave];
    }

    float bv = -__builtin_inff();
    int   bi = 2147483647;           // empty-segment sentinel == segment_min identity

    for (int i = start + lane; i < end; i += WAVE) {
        float v = values[i];
        // strictly-greater keeps the FIRST (lowest) index per lane, since i increases
        if (v > bv) { bv = v; bi = i; }
    }

    // Butterfly reduce across 64 lanes: max value, ties -> min index.
#pragma unroll
    for (int off = 32; off > 0; off >>= 1) {
        float ov = __shfl_xor(bv, off, WAVE);
        int   oi = __shfl_xor(bi, off, WAVE);
        if (ov > bv || (ov == bv && oi < bi)) { bv = ov; bi = oi; }
    }

    if (lane == 0) out[wave] = bi;
}

extern "C" void kernel_launch(void* const* d_in, const int* in_sizes, int n_in,
                              void* d_out, int out_size, void* d_ws, size_t ws_size,
                              hipStream_t stream) {
    const float* values = (const float*)d_in[0];
    const int*   ps32   = (const int*)d_in[1];
    const int n_seg = in_sizes[1];
    int* out = (int*)d_out;

    const int waves_per_block = 256 / WAVE;                 // 4
    const int grid = (n_seg + waves_per_block - 1) / waves_per_block;
    jagged_argmax_kernel<<<grid, 256, 0, stream>>>(values, ps32, n_seg, out);
}

// Round 2
// 150.266 us; speedup vs baseline: 1.8759x; 1.8759x over previous
//
#include <hip/hip_runtime.h>
#include <cstdint>

// Jagged per-segment argmax — round 2.
// One wave handles TWO segments (ILP: both segments' HBM load chains overlap,
// and the pair shares a prefix_sum boundary load). Per-lane float2-wide
// batches (128 elems/wave/iter). Cross-lane reduction via DPP on the VALU
// pipe (quad_perm xor1/xor2 + row_ror:4/8 + readlane combine) — zero DS-pipe
// ops, ~150 cy vs ~600 cy for the old 12x ds_swizzle shfl butterfly.
// Empty segments fall out naturally: bv=-inf everywhere -> cand=bi=INT32_MAX.

#define NEG_INF __int_as_float(0xFF800000u)
#define IMAX    0x7FFFFFFF

// DPP ctrl encodings (gfx9/CDNA): quad_perm = 8-bit perm, row_ror:N = 0x120+N
template<int CTRL>
__device__ __forceinline__ float dpp_max_step(float v) {
    int moved = __builtin_amdgcn_update_dpp((int)0xFF800000, __float_as_int(v),
                                            CTRL, 0xF, 0xF, false);
    return fmaxf(v, __int_as_float(moved));
}
template<int CTRL>
__device__ __forceinline__ int dpp_min_step(int v) {
    int moved = __builtin_amdgcn_update_dpp(IMAX, v, CTRL, 0xF, 0xF, false);
    return min(v, moved);
}

// Returns (uniform across wave) the min index attaining the wave-max of bv.
__device__ __forceinline__ int wave_argmax(float bv, int bi) {
    // 16-lane row max-reduce: xor1, xor2, ror4, ror8 (coverage = full row,
    // max is idempotent+commutative so rotate-based steps are valid)
    float m = bv;
    m = dpp_max_step<0xB1>(m);    // quad_perm(1,0,3,2)  = xor 1
    m = dpp_max_step<0x4E>(m);    // quad_perm(2,3,0,1)  = xor 2
    m = dpp_max_step<0x124>(m);   // row_ror:4
    m = dpp_max_step<0x128>(m);   // row_ror:8
    // cross-row combine via readlane (uniform values, no DS pipe)
    float r0 = __int_as_float(__builtin_amdgcn_readlane(__float_as_int(m), 0));
    float r1 = __int_as_float(__builtin_amdgcn_readlane(__float_as_int(m), 16));
    float r2 = __int_as_float(__builtin_amdgcn_readlane(__float_as_int(m), 32));
    float r3 = __int_as_float(__builtin_amdgcn_readlane(__float_as_int(m), 48));
    float maxv = fmaxf(fmaxf(r0, r1), fmaxf(r2, r3));
    // min index among lanes whose local max equals the wave max
    int cand = (bv == maxv) ? bi : IMAX;
    cand = dpp_min_step<0xB1>(cand);
    cand = dpp_min_step<0x4E>(cand);
    cand = dpp_min_step<0x124>(cand);
    cand = dpp_min_step<0x128>(cand);
    int i0 = __builtin_amdgcn_readlane(cand, 0);
    int i1 = __builtin_amdgcn_readlane(cand, 16);
    int i2 = __builtin_amdgcn_readlane(cand, 32);
    int i3 = __builtin_amdgcn_readlane(cand, 48);
    return min(min(i0, i1), min(i2, i3));
}

// Predicated pair-load + running (max, first-idx) update. v0 compared before
// v1 with strict '>' preserves first-index semantics.
__device__ __forceinline__ void upd_pair(const float* __restrict__ values,
                                         int i, int end, float& bv, int& bi) {
    float v0 = (i     < end) ? values[i]     : NEG_INF;
    float v1 = (i + 1 < end) ? values[i + 1] : NEG_INF;
    if (v0 > bv) { bv = v0; bi = i; }
    if (v1 > bv) { bv = v1; bi = i + 1; }
}

__global__ __launch_bounds__(256) void jagged_argmax_kernel(
    const float* __restrict__ values,
    const int*   __restrict__ ps32,   // prefix_sum words (int32 or int64 LE)
    int n_seg,
    int* __restrict__ out)
{
    const int pair = blockIdx.x * (blockDim.x >> 6) + ((int)threadIdx.x >> 6);
    const int lane = (int)threadIdx.x & 63;
    const int seg0 = pair * 2;
    if (seg0 >= n_seg) return;             // wave-uniform exit
    const bool has1 = (seg0 + 1) < n_seg;

    // int64 LE => word1 = high word of ps[0] (< 2^31) == 0; int32 => ps[1] >= 1
    const bool is64 = (ps32[1] == 0);
    const long long* ps64 = (const long long*)ps32;

    int s0, e0, e1;
    if (is64) {
        s0 = seg0 ? (int)ps64[seg0 - 1] : 0;
        e0 = (int)ps64[seg0];
        e1 = has1 ? (int)ps64[seg0 + 1] : e0;
    } else {
        s0 = seg0 ? ps32[seg0 - 1] : 0;
        e0 = ps32[seg0];
        e1 = has1 ? ps32[seg0 + 1] : e0;   // seg1 = [e0, e1)
    }

    float bv0 = NEG_INF, bv1 = NEG_INF;
    int   bi0 = IMAX,    bi1 = IMAX;

    // Peeled first batches for BOTH segments: 4 loads issue back-to-back so
    // the two HBM latency chains overlap.
    upd_pair(values, s0 + 2 * lane, e0, bv0, bi0);
    upd_pair(values, e0 + 2 * lane, e1, bv1, bi1);

    // Long-segment remainders (P(len>128) ~ 13.5%)
    for (int i = s0 + 2 * lane + 128; i < e0; i += 128)
        upd_pair(values, i, e0, bv0, bi0);
    for (int i = e0 + 2 * lane + 128; i < e1; i += 128)
        upd_pair(values, i, e1, bv1, bi1);

    // Two independent DPP reduce chains — compiler interleaves them.
    int idx0 = wave_argmax(bv0, bi0);
    int idx1 = wave_argmax(bv1, bi1);

    int myi = (lane == 0) ? idx0 : idx1;
    if (lane < (has1 ? 2 : 1)) out[seg0 + lane] = myi;
}

extern "C" void kernel_launch(void* const* d_in, const int* in_sizes, int n_in,
                              void* d_out, int out_size, void* d_ws, size_t ws_size,
                              hipStream_t stream) {
    const float* values = (const float*)d_in[0];
    const int*   ps32   = (const int*)d_in[1];
    const int n_seg = in_sizes[1];
    int* out = (int*)d_out;

    // 256 threads = 4 waves = 4 pairs = 8 segments per block
    const int segs_per_block = 8;
    const int grid = (n_seg + segs_per_block - 1) / segs_per_block;
    jagged_argmax_kernel<<<grid, 256, 0, stream>>>(values, ps32, n_seg, out);
}